// Round 3
// baseline (641.722 us; speedup 1.0000x reference)
//
#include <hip/hip_runtime.h>
#include <hip/hip_fp16.h>

#define NQ   13
#define DIM  8192
#define PI_F 3.14159265358979323846f
#define NT   512     // 2 groups x 256 threads; grid 256 -> 1 block/CU
#define NTG  256     // threads per item-group
#define NAMP 32      // amplitudes per thread (5-bit register window)

// fp16 state in LDS, pad +4 slots per 32 (proven layout from the 40.5us kernel).
#define NSLOT 9216   // half2 slots per item = 36.9 KB; two items = 73.7 KB

__device__ __forceinline__ int base0(int t) { return 36 * t; }
__device__ __forceinline__ int base2(int t, int q) { return 1152 * q + 4 * t + 4 * (t >> 3); }
__device__ __forceinline__ int slot1(int t, int j) { return 1152 * (t >> 5) + 36 * j + (t & 31); }

union F4H { float4 f; __half2 h[4]; };

__device__ __forceinline__ void rsincos(float x, float* s, float* c) {
  const float INV2PI = 0.15915494309189535f;
  const float TWOPI  = 6.283185307179586f;
  float r = x * INV2PI;
  r -= rintf(r);
  float ang = r * TWOPI;
  *s = __sinf(ang);
  *c = __cosf(ang);
}

// wave-local "barrier" (PAT0<->PAT1 both pin i-bits 11,12 to the wave id)
__device__ __forceinline__ void waveFence() {
  __builtin_amdgcn_wave_barrier();
  __threadfence_block();
  __builtin_amdgcn_wave_barrier();
}

// ---- fp32 helpers
__device__ __forceinline__ float2 f2fma(float s, float2 a, float2 b) {
  return make_float2(fmaf(s, a.x, b.x), fmaf(s, a.y, b.y));
}
__device__ __forceinline__ float2 f2add(float2 a, float2 b) {
  return make_float2(a.x + b.x, a.y + b.y);
}
__device__ __forceinline__ float2 f2sub(float2 a, float2 b) {
  return make_float2(a.x - b.x, a.y - b.y);
}
__device__ __forceinline__ float2 cphase(float2 v, float cs, float sn) {
  return make_float2(fmaf(cs, v.x, -sn * v.y), fmaf(cs, v.y, sn * v.x));
}
__device__ __forceinline__ float2 cmul(float2 a, float2 b) {
  return make_float2(fmaf(a.x, b.x, -a.y * b.y), fmaf(a.x, b.y, a.y * b.x));
}

template<int PAT>
__device__ __forceinline__ int ampIndex(int t, int j) {
  if constexpr (PAT == 0) return (t << 5) | j;
  else if constexpr (PAT == 1) return ((t >> 5) << 10) | (j << 5) | (t & 31);
  else return ((j >> 2) << 10) | (t << 2) | (j & 3);
}

// phase tree: s[j] = bias + sum over set bits of i(t,j) of w[bitpos]
template<int PAT>
__device__ __forceinline__ void buildTree(const float* __restrict__ w, float bias,
                                          int t, float* s) {
  float base = bias;
  if constexpr (PAT == 0) {
    #pragma unroll
    for (int k = 0; k < 8; k++) base += ((t >> k) & 1) ? w[5 + k] : 0.0f;
  } else {   // PAT2
    #pragma unroll
    for (int k = 0; k < 8; k++) base += ((t >> k) & 1) ? w[2 + k] : 0.0f;
  }
  constexpr int P[5] = { 0, 1,
                         (PAT == 0) ? 2 : 10,
                         (PAT == 0) ? 3 : 11,
                         (PAT == 0) ? 4 : 12 };
  s[0] = base;
  #pragma unroll
  for (int k = 0; k < 5; k++) {
    float wp = w[P[k]];
    #pragma unroll
    for (int m = 0; m < (1 << k); m++) s[m | (1 << k)] = s[m] + wp;
  }
}

// ---- fp32-register LDS access (b128 packed fp16 at the boundary)
__device__ __forceinline__ void loadA0f(const __half2* __restrict__ sAmp, int t, float2* amp) {
  const __half2* p = sAmp + base0(t);
  #pragma unroll
  for (int k = 0; k < 8; k++) {
    F4H u; u.f = *reinterpret_cast<const float4*>(p + 4 * k);
    #pragma unroll
    for (int c = 0; c < 4; c++) amp[4 * k + c] = __half22float2(u.h[c]);
  }
}
__device__ __forceinline__ void storeA0f(__half2* __restrict__ sAmp, int t, const float2* amp) {
  __half2* p = sAmp + base0(t);
  #pragma unroll
  for (int k = 0; k < 8; k++) {
    F4H u;
    #pragma unroll
    for (int c = 0; c < 4; c++) u.h[c] = __float22half2_rn(amp[4 * k + c]);
    *reinterpret_cast<float4*>(p + 4 * k) = u.f;
  }
}
__device__ __forceinline__ void loadA2f(const __half2* __restrict__ sAmp, int t, float2* amp) {
  #pragma unroll
  for (int q = 0; q < 8; q++) {
    F4H u; u.f = *reinterpret_cast<const float4*>(sAmp + base2(t, q));
    #pragma unroll
    for (int c = 0; c < 4; c++) amp[4 * q + c] = __half22float2(u.h[c]);
  }
}
__device__ __forceinline__ void storeA2f(__half2* __restrict__ sAmp, int t, const float2* amp) {
  #pragma unroll
  for (int q = 0; q < 8; q++) {
    F4H u;
    #pragma unroll
    for (int c = 0; c < 4; c++) u.h[c] = __float22half2_rn(amp[4 * q + c]);
    *reinterpret_cast<float4*>(sAmp + base2(t, q)) = u.f;
  }
}

// ---- fp16-register LDS access
__device__ __forceinline__ void loadA0h(const __half2* __restrict__ sAmp, int t, __half2* amp) {
  const __half2* p = sAmp + base0(t);
  #pragma unroll
  for (int k = 0; k < 8; k++) {
    F4H u; u.f = *reinterpret_cast<const float4*>(p + 4 * k);
    #pragma unroll
    for (int c = 0; c < 4; c++) amp[4 * k + c] = u.h[c];
  }
}
__device__ __forceinline__ void storeA0h(__half2* __restrict__ sAmp, int t, const __half2* amp) {
  __half2* p = sAmp + base0(t);
  #pragma unroll
  for (int k = 0; k < 8; k++) {
    F4H u;
    #pragma unroll
    for (int c = 0; c < 4; c++) u.h[c] = amp[4 * k + c];
    *reinterpret_cast<float4*>(p + 4 * k) = u.f;
  }
}
__device__ __forceinline__ void loadA1h(const __half2* __restrict__ sAmp, int t, __half2* amp) {
  #pragma unroll
  for (int j = 0; j < NAMP; j++) amp[j] = sAmp[slot1(t, j)];
}
__device__ __forceinline__ void storeA1h(__half2* __restrict__ sAmp, int t, const __half2* amp) {
  #pragma unroll
  for (int j = 0; j < NAMP; j++) sAmp[slot1(t, j)] = amp[j];
}

// ---- fp32 gate math
template<int KB>
__device__ __forceinline__ void fwht_bit(float2* amp) {
  #pragma unroll
  for (int j = 0; j < NAMP; j++) if (!(j & (1 << KB))) {
    int j1 = j | (1 << KB);
    float2 a0 = amp[j], a1 = amp[j1];
    amp[j]  = f2add(a0, a1);
    amp[j1] = f2sub(a0, a1);
  }
}
template<int KB>
__device__ __forceinline__ void applyRy(float2* amp, float ta, float sa) {
  #pragma unroll
  for (int j = 0; j < NAMP; j++) if (!(j & (1 << KB))) {
    int j1 = j | (1 << KB);
    amp[j]  = f2fma(-ta, amp[j1], amp[j]);
    amp[j1] = f2fma( sa, amp[j],  amp[j1]);
    amp[j]  = f2fma(-ta, amp[j1], amp[j]);
  }
}

// ---- fp16 packed gate math (v_pk_*_f16)
template<int KB>
__device__ __forceinline__ void fwht_bitH(__half2* amp) {
  #pragma unroll
  for (int j = 0; j < NAMP; j++) if (!(j & (1 << KB))) {
    int j1 = j | (1 << KB);
    __half2 a0 = amp[j], a1 = amp[j1];
    amp[j]  = __hadd2(a0, a1);
    amp[j1] = __hsub2(a0, a1);
  }
}
template<int KB>
__device__ __forceinline__ void applyRyH(__half2* amp, __half2 nta, __half2 sa) {
  #pragma unroll
  for (int j = 0; j < NAMP; j++) if (!(j & (1 << KB))) {
    int j1 = j | (1 << KB);
    amp[j]  = __hfma2(nta, amp[j1], amp[j]);
    amp[j1] = __hfma2(sa,  amp[j],  amp[j1]);
    amp[j]  = __hfma2(nta, amp[j1], amp[j]);
  }
}

// psi *= exp(i*phi(i)), phi = u + 0.5*(v^2 - A2); INIT writes unit phase
template<int PAT, bool INIT>
__device__ __forceinline__ void featureDiag(float2* amp,
                                            const float* __restrict__ wXp,
                                            const float* __restrict__ wAp,
                                            const float* __restrict__ consp, int t) {
  float u[NAMP], v[NAMP];
  buildTree<PAT>(wXp, consp[0], t, u);
  buildTree<PAT>(wAp, consp[1], t, v);
  float A2 = consp[2];
  #pragma unroll
  for (int j = 0; j < NAMP; j++) {
    float phi = u[j] + 0.5f * (v[j] * v[j] - A2);
    float sn, cs; rsincos(phi, &sn, &cs);
    if constexpr (INIT) amp[j] = make_float2(cs, sn);
    else                amp[j] = cphase(amp[j], cs, sn);
  }
}

// psi *= ENT(i)*exp(i*rho(i)) on PAT2 (window {0,1,10,11,12}); product tree
// split 16+16 to cap live registers
__device__ __forceinline__ void applyDiagPT2(float2* amp,
                                             const float* __restrict__ wb,
                                             const float* __restrict__ eR,
                                             const float* __restrict__ eI,
                                             float bias, int t) {
  float base = bias;
  #pragma unroll
  for (int k = 0; k < 8; k++) base += ((t >> k) & 1) ? wb[2 + k] : 0.0f;
  float2 c[16];
  { float sn, cs; rsincos(base, &sn, &cs); c[0] = make_float2(cs, sn); }
  constexpr int EB[4] = {0, 1, 10, 11};
  #pragma unroll
  for (int k = 0; k < 4; k++) {
    float2 e = make_float2(eR[EB[k]], eI[EB[k]]);
    #pragma unroll
    for (int m = 0; m < (1 << k); m++) c[m | (1 << k)] = cmul(c[m], e);
  }
  #pragma unroll
  for (int j = 0; j < 16; j++) {
    int i = ampIndex<2>(t, j);
    float sgn = (__popc(i & (i >> 1)) & 1) ? -1.0f : 1.0f;
    amp[j] = cphase(amp[j], c[j].x * sgn, c[j].y * sgn);
  }
  float2 e4 = make_float2(eR[12], eI[12]);
  #pragma unroll
  for (int j = 16; j < 32; j++) {
    int i = ampIndex<2>(t, j);
    float sgn = (__popc(i & (i >> 1)) & 1) ? -1.0f : 1.0f;
    float2 cc = cmul(c[j - 16], e4);
    amp[j] = cphase(amp[j], cc.x * sgn, cc.y * sgn);
  }
}

// Two items per block. Anti-phase pipeline: each slot, group0 loads phase s
// while group1 computes phase s-1; barrier; group0 computes s while group1
// loads s. All cross-wave LDS deps are barrier-protected (in-place windows).
__global__ __launch_bounds__(NT, 2) void qc_kernel(
    const float* __restrict__ xin,
    const float* __restrict__ thin,
    const float* __restrict__ bin,
    float* __restrict__ out) {
  __shared__ alignas(16) __half2 sAmp[2][NSLOT];
  __shared__ float gTA[65], gSA[65];      // fp32 shear coeffs (shared theta)
  __shared__ __half2 hNTA[65], hSA[65];   // packed (-ta,-ta),(sa,sa)
  __shared__ float gBbit[65];             // b by [l*13 + bitpos], bitpos = 12-q
  __shared__ float eBr[65], eBi[65];      // cos(b), sin(b)
  __shared__ float wX[2][13], wA[2][13];  // per-item -2x, -2a by bitpos
  __shared__ float cons[2][8];            // per-item 0:X 1:A 2:A2 3..7:-0.5*sum b_l
  __shared__ float red[NT / 64];

  const int t  = threadIdx.x;
  const int tt = t & (NTG - 1);
  const int g  = t >> 8;                  // item group 0/1
  const int b  = blockIdx.x;

  if (t < 2 * NQ) {
    int gg = (t < NQ) ? 0 : 1;
    int q  = (t < NQ) ? t : t - NQ;
    float xq = xin[(2 * b + gg) * NQ + q];
    float aq = PI_F - xq;
    wX[gg][12 - q] = -2.0f * xq;
    wA[gg][12 - q] = -2.0f * aq;
  }
  if (t < 65) {
    float av = thin[2 * t];
    float bv = thin[2 * t + 1];
    float ca = cosf(0.5f * av);
    float sa = sinf(0.5f * av);
    float ta = sa / (1.0f + ca);
    gTA[t] = ta;
    gSA[t] = sa;
    hNTA[t] = __float2half2_rn(-ta);
    hSA[t]  = __float2half2_rn(sa);
    int l = t / NQ, q = t % NQ;
    int s = l * NQ + (12 - q);
    gBbit[s] = bv;
    eBr[s] = cosf(bv);
    eBi[s] = sinf(bv);
  }
  __syncthreads();
  if (tt == 0) {
    float X = 0.f, A = 0.f, A2 = 0.f;
    for (int p = 0; p < NQ; p++) {
      float xq = -0.5f * wX[g][p], aq = -0.5f * wA[g][p];
      X += xq; A += aq; A2 += aq * aq;
    }
    cons[g][0] = X; cons[g][1] = A; cons[g][2] = A2;
    for (int l = 0; l < 5; l++) {
      float s = 0.f;
      for (int p = 0; p < NQ; p++) s += gBbit[l * NQ + p];
      cons[g][3 + l] = -0.5f * s;
    }
  }
  __syncthreads();

  float2  ampF[NAMP];
  __half2 ampH[NAMP];
  float acc = 0.0f;
  __half2* sA = sAmp[g];
  const float* wXg = wX[g];
  const float* wAg = wA[g];
  const float* cg  = cons[g];

  // phase p: 0 = init/FWHT(PAT0+PAT1); 1 = FWHT hi + featDiag2 + L0 window (PAT2)
  // even 2..10: layer (p/2-1) PAT0+PAT1 gates (p=10 fuses readout)
  // odd  3..9 : diag_l + L_{l+1} window gates (PAT2), l = (p-3)/2
  auto pipeLoad = [&](int p) {
    switch (p) {
      case 1: case 3: case 5: case 7: case 9:
        loadA2f(sA, tt, ampF); break;
      case 2: case 4: case 6: case 8: case 10:
        loadA0h(sA, tt, ampH); break;
      default: break;   // p==0: init phase, nothing to load
    }
  };

  auto pipeCompute = [&](int p) {
    switch (p) {
      case 0: {
        featureDiag<0, true>(ampF, wXg, wAg, cg, tt);
        fwht_bit<0>(ampF); fwht_bit<1>(ampF); fwht_bit<2>(ampF);
        fwht_bit<3>(ampF); fwht_bit<4>(ampF);
        storeA0f(sA, tt, ampF);
        waveFence();   // PAT0->PAT1 wave-private (i bits 11,12 pinned to wave)
        loadA1h(sA, tt, ampH);
        fwht_bitH<0>(ampH); fwht_bitH<1>(ampH); fwht_bitH<2>(ampH);
        fwht_bitH<3>(ampH); fwht_bitH<4>(ampH);
        storeA1h(sA, tt, ampH);
        break;
      }
      case 1: {
        fwht_bit<2>(ampF); fwht_bit<3>(ampF); fwht_bit<4>(ampF);
        featureDiag<2, false>(ampF, wXg, wAg, cg, tt);
        applyRy<0>(ampF, gTA[12], gSA[12]);
        applyRy<1>(ampF, gTA[11], gSA[11]);
        applyRy<2>(ampF, gTA[2],  gSA[2]);
        applyRy<3>(ampF, gTA[1],  gSA[1]);
        applyRy<4>(ampF, gTA[0],  gSA[0]);
        storeA2f(sA, tt, ampF);
        break;
      }
      case 2: case 4: case 6: case 8: {
        const int gl = (p / 2 - 1) * NQ;
        applyRyH<2>(ampH, hNTA[gl + 10], hSA[gl + 10]);
        applyRyH<3>(ampH, hNTA[gl + 9],  hSA[gl + 9]);
        applyRyH<4>(ampH, hNTA[gl + 8],  hSA[gl + 8]);
        storeA0h(sA, tt, ampH);
        waveFence();   // PAT0->PAT1 wave-private
        loadA1h(sA, tt, ampH);
        applyRyH<0>(ampH, hNTA[gl + 7], hSA[gl + 7]);
        applyRyH<1>(ampH, hNTA[gl + 6], hSA[gl + 6]);
        applyRyH<2>(ampH, hNTA[gl + 5], hSA[gl + 5]);
        applyRyH<3>(ampH, hNTA[gl + 4], hSA[gl + 4]);
        applyRyH<4>(ampH, hNTA[gl + 3], hSA[gl + 3]);
        storeA1h(sA, tt, ampH);
        break;
      }
      case 3: case 5: case 7: case 9: {
        const int l = (p - 3) / 2;
        const int gl = l * NQ, g1 = gl + NQ;
        applyDiagPT2(ampF, gBbit + gl, eBr + gl, eBi + gl, cg[3 + l], tt);
        applyRy<0>(ampF, gTA[g1 + 12], gSA[g1 + 12]);
        applyRy<1>(ampF, gTA[g1 + 11], gSA[g1 + 11]);
        applyRy<2>(ampF, gTA[g1 + 2],  gSA[g1 + 2]);
        applyRy<3>(ampF, gTA[g1 + 1],  gSA[g1 + 1]);
        applyRy<4>(ampF, gTA[g1 + 0],  gSA[g1 + 0]);
        storeA2f(sA, tt, ampF);
        break;
      }
      case 10: {
        const int gl = 4 * NQ;
        applyRyH<2>(ampH, hNTA[gl + 10], hSA[gl + 10]);
        applyRyH<3>(ampH, hNTA[gl + 9],  hSA[gl + 9]);
        applyRyH<4>(ampH, hNTA[gl + 8],  hSA[gl + 8]);
        storeA0h(sA, tt, ampH);
        waveFence();
        loadA1h(sA, tt, ampH);
        applyRyH<0>(ampH, hNTA[gl + 7], hSA[gl + 7]);
        applyRyH<1>(ampH, hNTA[gl + 6], hSA[gl + 6]);
        applyRyH<2>(ampH, hNTA[gl + 5], hSA[gl + 5]);
        applyRyH<3>(ampH, hNTA[gl + 4], hSA[gl + 4]);
        applyRyH<4>(ampH, hNTA[gl + 3], hSA[gl + 3]);
        // all L4 non-diagonal gates applied; trailing Rz invisible in |amp|^2
        #pragma unroll
        for (int j = 0; j < NAMP; j++) {
          int i = ampIndex<1>(tt, j);
          float2 a = __half22float2(ampH[j]);
          float p2 = fmaf(a.x, a.x, a.y * a.y);
          acc += (__popc(i) & 1) ? -p2 : p2;
        }
        break;
      }
      default: break;
    }
  };

  // ---- anti-phase pipeline: 11 phases, 12 slots, uniform barriers
  for (int s = 0; s < 12; ++s) {
    if (g == 0) { if (s < 11) pipeLoad(s); }
    else        { if (s >= 1) pipeCompute(s - 1); }
    __syncthreads();
    if (g == 0) { if (s < 11) pipeCompute(s); }
    else        { if (s < 11) pipeLoad(s); }
    __syncthreads();
  }

  // block reduction per item (raw scale 2^26)
  #pragma unroll
  for (int off = 32; off > 0; off >>= 1) acc += __shfl_down(acc, off, 64);
  if ((t & 63) == 0) red[t >> 6] = acc;
  __syncthreads();
  if (tt == 0) {
    float total = red[4 * g] + red[4 * g + 1] + red[4 * g + 2] + red[4 * g + 3];
    float logit = total * (1.0f / 67108864.0f) + bin[0];
    out[(2 * b + g) * 2 + 0] = -logit;
    out[(2 * b + g) * 2 + 1] = logit;
  }
}

extern "C" void kernel_launch(void* const* d_in, const int* in_sizes, int n_in,
                              void* d_out, int out_size, void* d_ws, size_t ws_size,
                              hipStream_t stream) {
  const float* x  = (const float*)d_in[0];
  const float* th = (const float*)d_in[1];
  const float* bi = (const float*)d_in[2];
  float* out = (float*)d_out;
  int B = in_sizes[0] / NQ;   // 512
  qc_kernel<<<B / 2, NT, 0, stream>>>(x, th, bi, out);
}

// Round 4
// 91.233 us; speedup vs baseline: 7.0339x; 7.0339x over previous
//
#include <hip/hip_runtime.h>
#include <hip/hip_fp16.h>

#define NQ   13
#define DIM  8192
#define PI_F 3.14159265358979323846f
#define NT   256     // 4 waves/block; grid 512 -> 2 blocks/CU
#define NAMP 32      // amplitudes per thread (5-bit register window)

// fp16 state in LDS, global layout L(i) = i + 4*(i>>5) (half2 slots).
#define NSLOT 9216

// Pattern H: i = (t<<5)|j. reg j bits 0..4 = i bits 0..4 (qubits 12..8);
//            lane bits 0,1 = i bits 5,6 (qubits 7,6) via DPP quad_perm.
//            Contiguous 32 slots -> 8x b128 (proven conflict-free PAT0).
// Pattern L: i = (j<<8)|((t&1)<<7)|((t&2)<<5)|(t>>2). reg j bits 0..4 =
//            i bits 8..12 (qubits 4..0); lane bit 0 = i bit 7 (qubit 5) DPP.
//            32x b32, stride 288 slots; verified 2 lanes/bank (free).
__device__ __forceinline__ int baseH(int t) { return 36 * t; }
__device__ __forceinline__ int baseL(int t) {
  int c = ((t & 1) << 7) | ((t & 2) << 5) | (t >> 2);
  return c + 4 * (c >> 5);
}

union F4H { float4 f; __half2 h[4]; };

__device__ __forceinline__ void rsincos(float x, float* s, float* c) {
  const float INV2PI = 0.15915494309189535f;
  const float TWOPI  = 6.283185307179586f;
  float r = x * INV2PI;
  r -= rintf(r);
  float ang = r * TWOPI;
  *s = __sinf(ang);
  *c = __cosf(ang);
}

// ---- fp32 helpers
__device__ __forceinline__ float2 f2fma(float s, float2 a, float2 b) {
  return make_float2(fmaf(s, a.x, b.x), fmaf(s, a.y, b.y));
}
__device__ __forceinline__ float2 f2add(float2 a, float2 b) {
  return make_float2(a.x + b.x, a.y + b.y);
}
__device__ __forceinline__ float2 f2sub(float2 a, float2 b) {
  return make_float2(a.x - b.x, a.y - b.y);
}
__device__ __forceinline__ float2 cphase(float2 v, float cs, float sn) {
  return make_float2(fmaf(cs, v.x, -sn * v.y), fmaf(cs, v.y, sn * v.x));
}
__device__ __forceinline__ float2 cmul(float2 a, float2 b) {
  return make_float2(fmaf(a.x, b.x, -a.y * b.y), fmaf(a.x, b.y, a.y * b.x));
}

// ---- DPP lane-xor (masks 1,2 only: quad_perm, pure VALU; R1-verified)
template<int MASK>
__device__ __forceinline__ int xorLaneI(int x) {
  if constexpr (MASK == 1)
    return __builtin_amdgcn_update_dpp(x, x, 0xB1, 0xF, 0xF, false);  // [1,0,3,2]
  else
    return __builtin_amdgcn_update_dpp(x, x, 0x4E, 0xF, 0xF, false);  // [2,3,0,1]
}
template<int MASK>
__device__ __forceinline__ __half2 xorLaneH(__half2 v) {
  union { __half2 h; int i; } u; u.h = v;
  u.i = xorLaneI<MASK>(u.i);
  return u.h;
}

// ---- LDS access, H pattern (8x b128; proven)
__device__ __forceinline__ void loadHh(const __half2* __restrict__ sAmp, int t, __half2* amp) {
  const __half2* p = sAmp + baseH(t);
  #pragma unroll
  for (int k = 0; k < 8; k++) {
    F4H u; u.f = *reinterpret_cast<const float4*>(p + 4 * k);
    #pragma unroll
    for (int c = 0; c < 4; c++) amp[4 * k + c] = u.h[c];
  }
}
__device__ __forceinline__ void storeHh(__half2* __restrict__ sAmp, int t, const __half2* amp) {
  __half2* p = sAmp + baseH(t);
  #pragma unroll
  for (int k = 0; k < 8; k++) {
    F4H u;
    #pragma unroll
    for (int c = 0; c < 4; c++) u.h[c] = amp[4 * k + c];
    *reinterpret_cast<float4*>(p + 4 * k) = u.f;
  }
}
// ---- LDS access, L pattern (32x b32, immediate offsets 288*j slots)
__device__ __forceinline__ void loadLh(const __half2* __restrict__ sAmp, int t, __half2* amp) {
  const __half2* p = sAmp + baseL(t);
  #pragma unroll
  for (int j = 0; j < NAMP; j++) amp[j] = p[288 * j];
}
__device__ __forceinline__ void storeLh(__half2* __restrict__ sAmp, int t, const __half2* amp) {
  __half2* p = sAmp + baseL(t);
  #pragma unroll
  for (int j = 0; j < NAMP; j++) p[288 * j] = amp[j];
}

// ---- fp32 register-bit gate math
template<int KB>
__device__ __forceinline__ void fwht_bit(float2* amp) {
  #pragma unroll
  for (int j = 0; j < NAMP; j++) if (!(j & (1 << KB))) {
    int j1 = j | (1 << KB);
    float2 a0 = amp[j], a1 = amp[j1];
    amp[j]  = f2add(a0, a1);
    amp[j1] = f2sub(a0, a1);
  }
}
template<int KB>
__device__ __forceinline__ void applyRy(float2* amp, float ta, float sa) {
  #pragma unroll
  for (int j = 0; j < NAMP; j++) if (!(j & (1 << KB))) {
    int j1 = j | (1 << KB);
    amp[j]  = f2fma(-ta, amp[j1], amp[j]);
    amp[j1] = f2fma( sa, amp[j],  amp[j1]);
    amp[j]  = f2fma(-ta, amp[j1], amp[j]);
  }
}

// ---- fp16 register-bit gate math (shear, R0-verified)
template<int KB>
__device__ __forceinline__ void applyRyH(__half2* amp, __half2 nta, __half2 sa) {
  #pragma unroll
  for (int j = 0; j < NAMP; j++) if (!(j & (1 << KB))) {
    int j1 = j | (1 << KB);
    amp[j]  = __hfma2(nta, amp[j1], amp[j]);
    amp[j1] = __hfma2(sa,  amp[j],  amp[j1]);
    amp[j]  = __hfma2(nta, amp[j1], amp[j]);
  }
}

// ---- fp16 DPP lane-bit gates (R1-verified math)
template<int MASK>
__device__ __forceinline__ void laneRyH(__half2* amp, __half2 c2, __half2 spm) {
  #pragma unroll
  for (int j = 0; j < NAMP; j++) {
    __half2 p = xorLaneH<MASK>(amp[j]);
    amp[j] = __hfma2(spm, p, __hmul2(c2, amp[j]));
  }
}
template<int MASK>
__device__ __forceinline__ void laneFwhtH(__half2* amp, __half2 sgn) {
  #pragma unroll
  for (int j = 0; j < NAMP; j++) {
    __half2 p = xorLaneH<MASK>(amp[j]);
    amp[j] = __hfma2(sgn, amp[j], p);
  }
}

// phase tree over the 5-bit register window.
// PAT 0 (H): t bit k -> i bit 5+k -> w[5+k]; window bitpos {0,1,2,3,4}
// PAT 1 (L): t bits {0,1,2..7} -> i bits {7,6,0..5}; window bitpos {8..12}
template<int PAT>
__device__ __forceinline__ void buildTree(const float* __restrict__ w, float bias,
                                          int t, float* s) {
  float base = bias;
  if constexpr (PAT == 0) {
    #pragma unroll
    for (int k = 0; k < 8; k++) base += ((t >> k) & 1) ? w[5 + k] : 0.0f;
  } else {
    constexpr int BM[8] = {7, 6, 0, 1, 2, 3, 4, 5};
    #pragma unroll
    for (int k = 0; k < 8; k++) base += ((t >> k) & 1) ? w[BM[k]] : 0.0f;
  }
  constexpr int PH[5] = {0, 1, 2, 3, 4};
  constexpr int PL[5] = {8, 9, 10, 11, 12};
  s[0] = base;
  #pragma unroll
  for (int k = 0; k < 5; k++) {
    float wp = w[(PAT == 0) ? PH[k] : PL[k]];
    #pragma unroll
    for (int m = 0; m < (1 << k); m++) s[m | (1 << k)] = s[m] + wp;
  }
}

// psi *= exp(i*phi(i)), phi = u + 0.5*(v^2 - A2); INIT writes unit phase
template<int PAT, bool INIT>
__device__ __forceinline__ void featureDiag(float2* amp,
                                            const float* __restrict__ wXp,
                                            const float* __restrict__ wAp,
                                            const float* __restrict__ consp, int t) {
  float u[NAMP], v[NAMP];
  buildTree<PAT>(wXp, consp[0], t, u);
  buildTree<PAT>(wAp, consp[1], t, v);
  float A2 = consp[2];
  #pragma unroll
  for (int j = 0; j < NAMP; j++) {
    float phi = u[j] + 0.5f * (v[j] * v[j] - A2);
    float sn, cs; rsincos(phi, &sn, &cs);
    if constexpr (INIT) amp[j] = make_float2(cs, sn);
    else                amp[j] = cphase(amp[j], cs, sn);
  }
}

// psi *= ENT(i)*exp(i*rho(i)): Rz_l + ENT diagonal, applied in pattern PAT.
// Product tree over the 4 low window bits + 5th-bit fold (register cap).
template<int PAT>
__device__ __forceinline__ void applyDiag(float2* amp,
                                          const float* __restrict__ wb,
                                          const float* __restrict__ eR,
                                          const float* __restrict__ eI,
                                          float bias, int t) {
  float base = bias;
  if constexpr (PAT == 0) {
    #pragma unroll
    for (int k = 0; k < 8; k++) base += ((t >> k) & 1) ? wb[5 + k] : 0.0f;
  } else {
    constexpr int BM[8] = {7, 6, 0, 1, 2, 3, 4, 5};
    #pragma unroll
    for (int k = 0; k < 8; k++) base += ((t >> k) & 1) ? wb[BM[k]] : 0.0f;
  }
  constexpr int E0 = (PAT == 0) ? 0 : 8;    // window bitpos of tree bits
  const int ct = (PAT == 0) ? 0 : (((t & 1) << 7) | ((t & 2) << 5) | (t >> 2));
  float2 c[16];
  { float sn, cs; rsincos(base, &sn, &cs); c[0] = make_float2(cs, sn); }
  #pragma unroll
  for (int k = 0; k < 4; k++) {
    float2 e = make_float2(eR[E0 + k], eI[E0 + k]);
    #pragma unroll
    for (int m = 0; m < (1 << k); m++) c[m | (1 << k)] = cmul(c[m], e);
  }
  #pragma unroll
  for (int j = 0; j < 16; j++) {
    int i = (PAT == 0) ? ((t << 5) | j) : ((j << 8) | ct);
    float sgn = (__popc(i & (i >> 1)) & 1) ? -1.0f : 1.0f;
    amp[j] = cphase(amp[j], c[j].x * sgn, c[j].y * sgn);
  }
  float2 e4 = make_float2(eR[E0 + 4], eI[E0 + 4]);
  #pragma unroll
  for (int j = 16; j < 32; j++) {
    int i = (PAT == 0) ? ((t << 5) | j) : ((j << 8) | ct);
    float sgn = (__popc(i & (i >> 1)) & 1) ? -1.0f : 1.0f;
    float2 cc = cmul(c[j - 16], e4);
    amp[j] = cphase(amp[j], cc.x * sgn, cc.y * sgn);
  }
}

// (256,1): lifted VGPR cap avoids the spill cliff; grid 512 -> 2 blocks/CU.
__global__ __launch_bounds__(NT, 1) void qc_kernel(
    const float* __restrict__ xin,
    const float* __restrict__ thin,
    const float* __restrict__ bin,
    float* __restrict__ out) {
  __shared__ alignas(16) __half2 sAmp[NSLOT];
  __shared__ float gTA[65], gSA[65];      // fp32 shear coeffs, l*13+qubit
  __shared__ __half2 hNTA[65], hSA[65];   // fp16 shear (-ta,-ta),(sa,sa)
  __shared__ __half2 hC2[65], hS2[65];    // fp16 rotation (c,c),(s,s) for DPP gates
  __shared__ float gBbit[65];             // Rz b by [l*13 + bitpos], bitpos = 12-q
  __shared__ float eBr[65], eBi[65];      // cos(b), sin(b) by [l*13 + bitpos]
  __shared__ float wX[13], wA[13];        // -2x, -2a by bitpos
  __shared__ float cons[8];               // 0:X 1:A 2:A2 3..7:-0.5*sum b_l
  __shared__ float red[NT / 64];

  const int t = threadIdx.x;
  const int lane = t & 63;
  const int b = blockIdx.x;

  if (t < NQ) {
    float xq = xin[b * NQ + t];
    float aq = PI_F - xq;
    wX[12 - t] = -2.0f * xq;
    wA[12 - t] = -2.0f * aq;
  }
  if (t < 65) {
    float av = thin[2 * t];
    float bv = thin[2 * t + 1];
    float ca = cosf(0.5f * av);
    float sa = sinf(0.5f * av);
    float ta = sa / (1.0f + ca);
    gTA[t] = ta;
    gSA[t] = sa;
    hNTA[t] = __float2half2_rn(-ta);
    hSA[t]  = __float2half2_rn(sa);
    hC2[t]  = __float2half2_rn(ca);
    hS2[t]  = __float2half2_rn(sa);
    int l = t / NQ, q = t % NQ;
    int s = l * NQ + (12 - q);
    gBbit[s] = bv;
    eBr[s] = cosf(bv);
    eBi[s] = sinf(bv);
  }
  __syncthreads();
  if (t == 0) {
    float X = 0.f, A = 0.f, A2 = 0.f;
    for (int p = 0; p < NQ; p++) {
      float xq = -0.5f * wX[p], aq = -0.5f * wA[p];
      X += xq; A += aq; A2 += aq * aq;
    }
    cons[0] = X; cons[1] = A; cons[2] = A2;
    for (int l = 0; l < 5; l++) {
      float s = 0.f;
      for (int p = 0; p < NQ; p++) s += gBbit[l * NQ + p];
      cons[3 + l] = -0.5f * s;
    }
  }
  __syncthreads();

  const __half2 P1 = __float2half2_rn(1.0f), M1 = __float2half2_rn(-1.0f);

  // ---- S0 [H]: init psi = exp(i*phi1); FWHT i-bits 0..4 (reg fp32),
  //              5,6 (DPP fp16)
  {
    float2 ampF[NAMP];
    featureDiag<0, true>(ampF, wX, wA, cons, t);
    fwht_bit<0>(ampF); fwht_bit<1>(ampF); fwht_bit<2>(ampF);
    fwht_bit<3>(ampF); fwht_bit<4>(ampF);
    __half2 ampH[NAMP];
    #pragma unroll
    for (int j = 0; j < NAMP; j++) ampH[j] = __float22half2_rn(ampF[j]);
    laneFwhtH<1>(ampH, (lane & 1) ? M1 : P1);   // i bit 5
    laneFwhtH<2>(ampH, (lane & 2) ? M1 : P1);   // i bit 6
    storeHh(sAmp, t, ampH);
  }
  __syncthreads();

  // ---- S1 [L]: FWHT i-bit 7 (DPP fp16), 8..12 (reg fp32); featDiag2;
  //              L-gates of layer 0: q2,q1,q0 fp32; q4,q3 fp16; q5 DPP fp16
  {
    __half2 ampH[NAMP];
    loadLh(sAmp, t, ampH);
    laneFwhtH<1>(ampH, (lane & 1) ? M1 : P1);   // i bit 7
    float2 ampF[NAMP];
    #pragma unroll
    for (int j = 0; j < NAMP; j++) ampF[j] = __half22float2(ampH[j]);
    fwht_bit<0>(ampF); fwht_bit<1>(ampF); fwht_bit<2>(ampF);
    fwht_bit<3>(ampF); fwht_bit<4>(ampF);       // i bits 8..12
    featureDiag<1, false>(ampF, wX, wA, cons, t);
    applyRy<2>(ampF, gTA[2], gSA[2]);           // qubit 2
    applyRy<3>(ampF, gTA[1], gSA[1]);           // qubit 1
    applyRy<4>(ampF, gTA[0], gSA[0]);           // qubit 0
    #pragma unroll
    for (int j = 0; j < NAMP; j++) ampH[j] = __float22half2_rn(ampF[j]);
    applyRyH<0>(ampH, hNTA[4], hSA[4]);         // qubit 4
    applyRyH<1>(ampH, hNTA[3], hSA[3]);         // qubit 3
    { __half2 s2 = hS2[5];
      laneRyH<1>(ampH, hC2[5], (lane & 1) ? s2 : __hneg2(s2)); }  // qubit 5
    storeLh(sAmp, t, ampH);
  }
  __syncthreads();

  // ---- S2/S4 [H] + S3/S5 [L]: Hg(l)+diag_l+Hg(l+1), Lg(l+1)+diag_{l+1}+Lg(l+2)
  for (int l = 0; l < 4; l += 2) {
    const int g = l * NQ, g1 = g + NQ, g2 = g1 + NQ;
    // H phase: H-gates of layer l, diag_l, H-gates of layer l+1
    {
      __half2 ampH[NAMP];
      loadHh(sAmp, t, ampH);
      { __half2 s2 = hS2[g + 7];
        laneRyH<1>(ampH, hC2[g + 7], (lane & 1) ? s2 : __hneg2(s2)); }
      { __half2 s2 = hS2[g + 6];
        laneRyH<2>(ampH, hC2[g + 6], (lane & 2) ? s2 : __hneg2(s2)); }
      applyRyH<2>(ampH, hNTA[g + 10], hSA[g + 10]);
      applyRyH<3>(ampH, hNTA[g + 9],  hSA[g + 9]);
      applyRyH<4>(ampH, hNTA[g + 8],  hSA[g + 8]);
      float2 ampF[NAMP];
      #pragma unroll
      for (int j = 0; j < NAMP; j++) ampF[j] = __half22float2(ampH[j]);
      applyRy<0>(ampF, gTA[g + 12], gSA[g + 12]);
      applyRy<1>(ampF, gTA[g + 11], gSA[g + 11]);
      applyDiag<0>(ampF, gBbit + g, eBr + g, eBi + g, cons[3 + l], t);
      applyRy<0>(ampF, gTA[g1 + 12], gSA[g1 + 12]);
      applyRy<1>(ampF, gTA[g1 + 11], gSA[g1 + 11]);
      #pragma unroll
      for (int j = 0; j < NAMP; j++) ampH[j] = __float22half2_rn(ampF[j]);
      applyRyH<2>(ampH, hNTA[g1 + 10], hSA[g1 + 10]);
      applyRyH<3>(ampH, hNTA[g1 + 9],  hSA[g1 + 9]);
      applyRyH<4>(ampH, hNTA[g1 + 8],  hSA[g1 + 8]);
      { __half2 s2 = hS2[g1 + 7];
        laneRyH<1>(ampH, hC2[g1 + 7], (lane & 1) ? s2 : __hneg2(s2)); }
      { __half2 s2 = hS2[g1 + 6];
        laneRyH<2>(ampH, hC2[g1 + 6], (lane & 2) ? s2 : __hneg2(s2)); }
      storeHh(sAmp, t, ampH);
    }
    __syncthreads();
    // L phase: L-gates of layer l+1, diag_{l+1}, L-gates of layer l+2
    {
      __half2 ampH[NAMP];
      loadLh(sAmp, t, ampH);
      { __half2 s2 = hS2[g1 + 5];
        laneRyH<1>(ampH, hC2[g1 + 5], (lane & 1) ? s2 : __hneg2(s2)); }
      applyRyH<0>(ampH, hNTA[g1 + 4], hSA[g1 + 4]);
      applyRyH<1>(ampH, hNTA[g1 + 3], hSA[g1 + 3]);
      float2 ampF[NAMP];
      #pragma unroll
      for (int j = 0; j < NAMP; j++) ampF[j] = __half22float2(ampH[j]);
      applyRy<2>(ampF, gTA[g1 + 2], gSA[g1 + 2]);
      applyRy<3>(ampF, gTA[g1 + 1], gSA[g1 + 1]);
      applyRy<4>(ampF, gTA[g1 + 0], gSA[g1 + 0]);
      applyDiag<1>(ampF, gBbit + g1, eBr + g1, eBi + g1, cons[3 + l + 1], t);
      applyRy<2>(ampF, gTA[g2 + 2], gSA[g2 + 2]);
      applyRy<3>(ampF, gTA[g2 + 1], gSA[g2 + 1]);
      applyRy<4>(ampF, gTA[g2 + 0], gSA[g2 + 0]);
      #pragma unroll
      for (int j = 0; j < NAMP; j++) ampH[j] = __float22half2_rn(ampF[j]);
      applyRyH<0>(ampH, hNTA[g2 + 4], hSA[g2 + 4]);
      applyRyH<1>(ampH, hNTA[g2 + 3], hSA[g2 + 3]);
      { __half2 s2 = hS2[g2 + 5];
        laneRyH<1>(ampH, hC2[g2 + 5], (lane & 1) ? s2 : __hneg2(s2)); }
      storeLh(sAmp, t, ampH);
    }
    __syncthreads();
  }

  // ---- S6 [H]: H-gates of layer 4; readout (trailing Rz_4 invisible)
  float acc = 0.0f;
  {
    const int g = 4 * NQ;
    __half2 ampH[NAMP];
    loadHh(sAmp, t, ampH);
    { __half2 s2 = hS2[g + 7];
      laneRyH<1>(ampH, hC2[g + 7], (lane & 1) ? s2 : __hneg2(s2)); }
    { __half2 s2 = hS2[g + 6];
      laneRyH<2>(ampH, hC2[g + 6], (lane & 2) ? s2 : __hneg2(s2)); }
    applyRyH<2>(ampH, hNTA[g + 10], hSA[g + 10]);
    applyRyH<3>(ampH, hNTA[g + 9],  hSA[g + 9]);
    applyRyH<4>(ampH, hNTA[g + 8],  hSA[g + 8]);
    float2 ampF[NAMP];
    #pragma unroll
    for (int j = 0; j < NAMP; j++) ampF[j] = __half22float2(ampH[j]);
    applyRy<0>(ampF, gTA[g + 12], gSA[g + 12]);
    applyRy<1>(ampF, gTA[g + 11], gSA[g + 11]);
    int pt = __popc(t) & 1;
    #pragma unroll
    for (int j = 0; j < NAMP; j++) {
      float p2 = fmaf(ampF[j].x, ampF[j].x, ampF[j].y * ampF[j].y);
      acc += ((pt + __popc(j)) & 1) ? -p2 : p2;
    }
  }

  // block reduction (raw scale 2^26)
  #pragma unroll
  for (int off = 32; off > 0; off >>= 1) acc += __shfl_down(acc, off, 64);
  if ((t & 63) == 0) red[t >> 6] = acc;
  __syncthreads();
  if (t == 0) {
    float total = red[0] + red[1] + red[2] + red[3];
    float logit = total * (1.0f / 67108864.0f) + bin[0];
    out[b * 2 + 0] = -logit;
    out[b * 2 + 1] = logit;
  }
}

extern "C" void kernel_launch(void* const* d_in, const int* in_sizes, int n_in,
                              void* d_out, int out_size, void* d_ws, size_t ws_size,
                              hipStream_t stream) {
  const float* x  = (const float*)d_in[0];
  const float* th = (const float*)d_in[1];
  const float* bi = (const float*)d_in[2];
  float* out = (float*)d_out;
  int B = in_sizes[0] / NQ;   // 512
  qc_kernel<<<B, NT, 0, stream>>>(x, th, bi, out);
}